// Round 2
// baseline (3011.070 us; speedup 1.0000x reference)
//
#include <hip/hip_runtime.h>
#include <cstdint>
#include <cstddef>

#define DI __device__ __forceinline__

typedef __bf16 bf16x8 __attribute__((ext_vector_type(8)));
typedef float  f32x4  __attribute__((ext_vector_type(4)));
typedef unsigned short ushort_t;

constexpr int BATCH = 1024;
constexpr int HID   = 2048;
constexpr int IN    = 76;
constexpr int SENC  = 49;
constexpr int TDEC  = 25;
constexpr int KX    = 128;          // x padded to 128 cols
constexpr int KP    = KX + HID;     // 2176 packed K
constexpr int BK    = 64;
constexpr int KTT   = KP / BK;      // 34 K-steps
constexpr int OSTR  = TDEC * IN;    // 1900 (row stride of decoder_inputs and d_out)

DI unsigned short f2bf(float f) {
  union { float f; unsigned u; } v; v.f = f;
  unsigned u = v.u;
  return (unsigned short)((u + 0x7fffu + ((u >> 16) & 1u)) >> 16);  // RTNE
}

DI f32x4 mfma16(bf16x8 a, bf16x8 b, f32x4 c) {
  return __builtin_amdgcn_mfma_f32_16x16x32_bf16(a, b, c, 0, 0, 0);
}

DI void gload_lds16(const void* g, void* l) {
  __builtin_amdgcn_global_load_lds((const __attribute__((address_space(1))) void*)g,
                                   (__attribute__((address_space(3))) void*)l,
                                   16, 0, 0);
}

DI float sigmoidf_(float x) { return 1.0f / (1.0f + __expf(-x)); }
DI float tanhf_(float x)    { return 1.0f - 2.0f / (1.0f + __expf(2.0f * x)); }

// ---------------- packing kernels (run once per launch) ----------------

__global__ void pack_W(const float* __restrict__ Wih, const float* __restrict__ Whh,
                       ushort_t* __restrict__ Wp) {
  int idx = blockIdx.x * 256 + threadIdx.x;
  if (idx >= 6144 * KP) return;
  int n = idx / KP;
  int k = idx - n * KP;
  float v = 0.f;
  if (k < IN)        v = Wih[(size_t)n * IN + k];
  else if (k >= KX)  v = Whh[(size_t)n * HID + (k - KX)];
  Wp[idx] = f2bf(v);
}

__global__ void pack_xe(const float* __restrict__ enc, ushort_t* __restrict__ xe) {
  int idx = blockIdx.x * 256 + threadIdx.x;
  if (idx >= SENC * BATCH * KX) return;
  int t = idx >> 17;
  int rem = idx & 131071;
  int b = rem >> 7, k = rem & 127;
  float v = (k < IN) ? enc[(size_t)b * (SENC * IN) + t * IN + k] : 0.f;
  xe[idx] = f2bf(v);
}

__global__ void pack_xd0(const float* __restrict__ dec, ushort_t* __restrict__ xd) {
  int idx = blockIdx.x * 256 + threadIdx.x;
  if (idx >= BATCH * KX) return;
  int b = idx >> 7, k = idx & 127;
  float v = (k < IN) ? dec[(size_t)b * OSTR + k] : 0.f;
  xd[idx] = f2bf(v);
}

__global__ void pack_fc(const float* __restrict__ fcw, ushort_t* __restrict__ Wfc) {
  int idx = blockIdx.x * 256 + threadIdx.x;
  if (idx >= 80 * HID) return;
  int n = idx >> 11, k = idx & 2047;
  float v = (n < IN) ? fcw[(size_t)n * HID + k] : 0.f;
  Wfc[idx] = f2bf(v);
}

// ---------------- fused GRU step, phase-split schedule (T3+T4+T5) ----------------
// grid 256 (8 m-groups x 32 n-groups), block 512 (8 waves, 4x2 over 128x64 tile)
// 3-buffer LDS pipeline, 2 tiles prefetched ahead, counted vmcnt(5) in steady state.
__global__ __launch_bounds__(512, 2) void gru_step_kernel(
    const ushort_t* __restrict__ x,    // [1024][128] bf16
    const ushort_t* __restrict__ hbp,  // [1024][2048] bf16 h_prev
    const float*    __restrict__ hfp,  // [1024][2048] f32  h_prev
    const ushort_t* __restrict__ Wp,   // [6144][2176] bf16
    const float*    __restrict__ b_ih,
    const float*    __restrict__ b_hh,
    float*          __restrict__ hfn,  // [1024][2048] f32  h_new
    ushort_t*       __restrict__ hbn)  // [1024][2048] bf16 h_new
{
  __shared__ ushort_t lds[3][(128 + 192) * BK];   // A 128x64 + B 192x64, 3 buffers = 120 KB

  const int tid  = threadIdx.x;
  const int lane = tid & 63;
  const int wid  = tid >> 6;
  const int bid  = blockIdx.x;
  // XCD swizzle: n-group constant per XCD (bid%8) -> W panel reused from one L2
  const int n_grp = (bid & 7) + 8 * (bid >> 6);   // 0..31
  const int m_grp = (bid >> 3) & 7;               // 0..7
  const int row0  = m_grp * 128;
  const int col0  = n_grp * 64;
  const int wm = wid >> 1, wn = wid & 1;

  // staging: chunk row = lane>>3, source col XOR-preswizzled so that the
  // linear global_load_lds destination holds the (row&7)-XOR-swizzled layout
  const int srow  = lane >> 3;
  const int swcol = (((lane & 7) ^ (srow & 7)) << 3);   // elements

  const f32x4 Z4 = {0.f, 0.f, 0.f, 0.f};
  f32x4 accr[2][2], accz[2][2], accin[2][2], accN[2][2];
  #pragma unroll
  for (int a = 0; a < 2; ++a)
    #pragma unroll
    for (int b = 0; b < 2; ++b) { accr[a][b] = Z4; accz[a][b] = Z4; accin[a][b] = Z4; accN[a][b] = Z4; }

  // fragment-read constants (consumer-side XOR swizzle)
  const int lr  = lane & 15;
  const int bc  = (lane >> 4) * 16;                       // byte col, pre-swizzle
  const int ksw0 = ((bc)      ^ ((lane & 7) << 4)) >> 1;  // element offsets
  const int ksw1 = ((64 + bc) ^ ((lane & 7) << 4)) >> 1;

  auto stage = [&](int buf, int kt) {
    const ushort_t* asrc; int astr, ak0;
    if (kt < 2) { asrc = x;   astr = KX;  ak0 = kt * BK; }
    else        { asrc = hbp; astr = HID; ak0 = (kt - 2) * BK; }
    ushort_t* Lb = &lds[buf][0];
    #pragma unroll
    for (int c = 0; c < 2; ++c) {                 // A: 2 chunks/wave (1 KB each)
      const int chunk = wid * 2 + c;
      const ushort_t* g = asrc + (size_t)(row0 + chunk * 8 + srow) * astr + ak0 + swcol;
      gload_lds16(g, Lb + chunk * 512);
    }
    const int wk0 = kt * BK;
    #pragma unroll
    for (int c = 0; c < 3; ++c) {                 // B: 3 chunks/wave
      const int chunk = wid * 3 + c;
      const int brow = chunk * 8 + srow;          // 0..191 (gate*64 + col)
      const int gg = brow >> 6, wi = brow & 63;
      const ushort_t* g = Wp + (size_t)(gg * HID + col0 + wi) * KP + wk0 + swcol;
      gload_lds16(g, Lb + 128 * BK + chunk * 512);
    }
  };

  // prologue: 2 tiles in flight
  stage(0, 0);
  stage(1, 1);
  asm volatile("s_waitcnt vmcnt(5)" ::: "memory");   // tile 0 staged, tile 1 in flight
  __builtin_amdgcn_s_barrier();

  for (int kt = 0; kt < KTT; ++kt) {
    const ushort_t* Ab = &lds[kt % 3][0];
    const ushort_t* Bb = &lds[kt % 3][128 * BK];

    // ---------- phase 0 (ks = 0) ----------
    bf16x8 af0[2], bg0[3][2];
    #pragma unroll
    for (int fm = 0; fm < 2; ++fm)
      af0[fm] = *reinterpret_cast<const bf16x8*>(&Ab[(wm * 32 + fm * 16 + lr) * BK + ksw0]);
    #pragma unroll
    for (int g = 0; g < 3; ++g)
      #pragma unroll
      for (int fn = 0; fn < 2; ++fn)
        bg0[g][fn] = *reinterpret_cast<const bf16x8*>(&Bb[(g * 64 + wn * 32 + fn * 16 + lr) * BK + ksw0]);
    if (kt + 2 < KTT) stage((kt + 2) % 3, kt + 2);   // prefetch 2 ahead
    __builtin_amdgcn_sched_barrier(0);
    __builtin_amdgcn_s_barrier();
    asm volatile("s_waitcnt lgkmcnt(0)" ::: "memory");
    __builtin_amdgcn_sched_barrier(0);
    __builtin_amdgcn_s_setprio(1);
    #pragma unroll
    for (int fm = 0; fm < 2; ++fm)
      #pragma unroll
      for (int fn = 0; fn < 2; ++fn) {
        accr[fm][fn] = mfma16(af0[fm], bg0[0][fn], accr[fm][fn]);
        accz[fm][fn] = mfma16(af0[fm], bg0[1][fn], accz[fm][fn]);
        accN[fm][fn] = mfma16(af0[fm], bg0[2][fn], accN[fm][fn]);
      }
    __builtin_amdgcn_s_setprio(0);
    __builtin_amdgcn_sched_barrier(0);
    __builtin_amdgcn_s_barrier();

    // ---------- phase 1 (ks = 1) ----------
    bf16x8 af1[2], bg1[3][2];
    #pragma unroll
    for (int fm = 0; fm < 2; ++fm)
      af1[fm] = *reinterpret_cast<const bf16x8*>(&Ab[(wm * 32 + fm * 16 + lr) * BK + ksw1]);
    #pragma unroll
    for (int g = 0; g < 3; ++g)
      #pragma unroll
      for (int fn = 0; fn < 2; ++fn)
        bg1[g][fn] = *reinterpret_cast<const bf16x8*>(&Bb[(g * 64 + wn * 32 + fn * 16 + lr) * BK + ksw1]);
    // counted wait: tile kt+1 must be staged before next iteration reads it;
    // tile kt+2's 5 loads stay in flight (never drain to 0 in steady state)
    if (kt + 2 < KTT) { asm volatile("s_waitcnt vmcnt(5)" ::: "memory"); }
    else              { asm volatile("s_waitcnt vmcnt(0)" ::: "memory"); }
    __builtin_amdgcn_sched_barrier(0);
    __builtin_amdgcn_s_barrier();
    asm volatile("s_waitcnt lgkmcnt(0)" ::: "memory");
    __builtin_amdgcn_sched_barrier(0);
    __builtin_amdgcn_s_setprio(1);
    #pragma unroll
    for (int fm = 0; fm < 2; ++fm)
      #pragma unroll
      for (int fn = 0; fn < 2; ++fn) {
        accr[fm][fn] = mfma16(af1[fm], bg1[0][fn], accr[fm][fn]);
        accz[fm][fn] = mfma16(af1[fm], bg1[1][fn], accz[fm][fn]);
        accN[fm][fn] = mfma16(af1[fm], bg1[2][fn], accN[fm][fn]);
      }
    __builtin_amdgcn_s_setprio(0);
    __builtin_amdgcn_sched_barrier(0);
    __builtin_amdgcn_s_barrier();

    if (kt == 1) {   // n-gate: save x-part (i_n), restart accumulator for h-part (h_n)
      #pragma unroll
      for (int a = 0; a < 2; ++a)
        #pragma unroll
        for (int b = 0; b < 2; ++b) { accin[a][b] = accN[a][b]; accN[a][b] = Z4; }
    }
  }

  // epilogue: gates + recurrence (C/D layout: col = lane&15, row = (lane>>4)*4 + q)
  const int lqb = (lane >> 4) * 4;
  #pragma unroll
  for (int fn = 0; fn < 2; ++fn) {
    const int j = col0 + wn * 32 + fn * 16 + lr;
    const float br  = b_ih[j] + b_hh[j];
    const float bz  = b_ih[HID + j] + b_hh[HID + j];
    const float bin = b_ih[2 * HID + j];
    const float bhn = b_hh[2 * HID + j];
    #pragma unroll
    for (int fm = 0; fm < 2; ++fm) {
      #pragma unroll
      for (int q = 0; q < 4; ++q) {
        const int row = row0 + wm * 32 + fm * 16 + lqb + q;
        const size_t off = (size_t)row * HID + j;
        const float hp = hfp[off];
        const float rr = sigmoidf_(accr[fm][fn][q] + br);
        const float zz = sigmoidf_(accz[fm][fn][q] + bz);
        const float nn = tanhf_(accin[fm][fn][q] + bin + rr * (accN[fm][fn][q] + bhn));
        const float hv = (1.0f - zz) * nn + zz * hp;
        hfn[off] = hv;
        hbn[off] = f2bf(hv);
      }
    }
  }
}

// ---------------- decoder fc: out = prev + h_new @ fc_w^T + fc_b; also emit next x (bf16) ----
__global__ __launch_bounds__(256) void fc_kernel(
    const ushort_t* __restrict__ hb,    // [1024][2048] bf16 h_new
    const ushort_t* __restrict__ Wfc,   // [80][2048] bf16
    const float*    __restrict__ fc_b,
    const float*    __restrict__ prev,  // row stride OSTR
    float*          __restrict__ outp,  // d_out + t*IN, row stride OSTR
    ushort_t*       __restrict__ xd)    // [1024][128] bf16 next input
{
  __shared__ float red[4][16][80];
  const int tid = threadIdx.x, lane = tid & 63, wid = tid >> 6;
  const int r0 = blockIdx.x * 16;
  const int lr = lane & 15, lk = (lane >> 4) * 8;
  const f32x4 Z4 = {0.f, 0.f, 0.f, 0.f};
  f32x4 acc[5];
  #pragma unroll
  for (int f = 0; f < 5; ++f) acc[f] = Z4;
  const int kbase = wid * 512;
  #pragma unroll
  for (int ks = 0; ks < 16; ++ks) {
    const int k = kbase + ks * 32 + lk;
    bf16x8 a = *reinterpret_cast<const bf16x8*>(&hb[(size_t)(r0 + lr) * HID + k]);
    #pragma unroll
    for (int f = 0; f < 5; ++f) {
      bf16x8 b = *reinterpret_cast<const bf16x8*>(&Wfc[(size_t)(f * 16 + lr) * HID + k]);
      acc[f] = mfma16(a, b, acc[f]);
    }
  }
  #pragma unroll
  for (int f = 0; f < 5; ++f)
    #pragma unroll
    for (int q = 0; q < 4; ++q)
      red[wid][(lane >> 4) * 4 + q][f * 16 + lr] = acc[f][q];
  __syncthreads();

  const int rowi = tid >> 4;          // 0..15
  const int j0   = (tid & 15) * 8;    // 0..120
  const int b_   = r0 + rowi;
  #pragma unroll
  for (int jj = 0; jj < 8; ++jj) {
    const int j = j0 + jj;
    float ov = 0.f;
    if (j < IN) {
      float s = red[0][rowi][j] + red[1][rowi][j] + red[2][rowi][j] + red[3][rowi][j];
      ov = prev[(size_t)b_ * OSTR + j] + fc_b[j] + s;
      outp[(size_t)b_ * OSTR + j] = ov;
    }
    xd[b_ * KX + j] = f2bf(j < IN ? ov : 0.f);
  }
}

// ---------------- host launch ----------------
extern "C" void kernel_launch(void* const* d_in, const int* in_sizes, int n_in,
                              void* d_out, int out_size, void* d_ws, size_t ws_size,
                              hipStream_t stream) {
  const float* enc = (const float*)d_in[0];
  const float* dec = (const float*)d_in[1];
  const float* Wih = (const float*)d_in[2];
  const float* Whh = (const float*)d_in[3];
  const float* bih = (const float*)d_in[4];
  const float* bhh = (const float*)d_in[5];
  const float* fcw = (const float*)d_in[6];
  const float* fcb = (const float*)d_in[7];
  float* out = (float*)d_out;

  char* ws = (char*)d_ws;
  ushort_t* Wp  = (ushort_t*)ws;  ws += (size_t)6144 * KP * 2;          // 26.7 MB
  ushort_t* xe  = (ushort_t*)ws;  ws += (size_t)SENC * BATCH * KX * 2;  // 12.8 MB
  ushort_t* xd  = (ushort_t*)ws;  ws += (size_t)BATCH * KX * 2;         // 256 KB
  ushort_t* Wfc = (ushort_t*)ws;  ws += (size_t)80 * HID * 2;           // 320 KB
  float* hf0 = (float*)ws;        ws += (size_t)BATCH * HID * 4;
  float* hf1 = (float*)ws;        ws += (size_t)BATCH * HID * 4;
  ushort_t* hb0 = (ushort_t*)ws;  ws += (size_t)BATCH * HID * 2;
  ushort_t* hb1 = (ushort_t*)ws;  ws += (size_t)BATCH * HID * 2;
  float* hf[2] = {hf0, hf1};
  ushort_t* hbp[2] = {hb0, hb1};

  pack_W  <<<(6144 * KP + 255) / 256, 256, 0, stream>>>(Wih, Whh, Wp);
  pack_xe <<<(SENC * BATCH * KX + 255) / 256, 256, 0, stream>>>(enc, xe);
  pack_xd0<<<(BATCH * KX + 255) / 256, 256, 0, stream>>>(dec, xd);
  pack_fc <<<(80 * HID + 255) / 256, 256, 0, stream>>>(fcw, Wfc);
  hipMemsetAsync(hf0, 0, (size_t)BATCH * HID * 4, stream);
  hipMemsetAsync(hb0, 0, (size_t)BATCH * HID * 2, stream);

  for (int s = 0; s < SENC + TDEC; ++s) {
    const ushort_t* xsrc = (s < SENC) ? (xe + (size_t)s * BATCH * KX) : xd;
    gru_step_kernel<<<256, 512, 0, stream>>>(xsrc, hbp[s & 1], hf[s & 1], Wp, bih, bhh,
                                             hf[(s + 1) & 1], hbp[(s + 1) & 1]);
    if (s >= SENC) {
      const int t = s - SENC;
      const float* prev = (t == 0) ? dec : (out + (size_t)(t - 1) * IN);
      fc_kernel<<<64, 256, 0, stream>>>(hbp[(s + 1) & 1], Wfc, fcb, prev,
                                        out + (size_t)t * IN, xd);
    }
  }
}

// Round 3
// 2732.588 us; speedup vs baseline: 1.1019x; 1.1019x over previous
//
#include <hip/hip_runtime.h>
#include <cstdint>
#include <cstddef>

#define DI __device__ __forceinline__

typedef __bf16 bf16x8 __attribute__((ext_vector_type(8)));
typedef float  f32x4  __attribute__((ext_vector_type(4)));
typedef unsigned short ushort_t;

constexpr int BATCH = 1024;
constexpr int HID   = 2048;
constexpr int IN    = 76;
constexpr int SENC  = 49;
constexpr int TDEC  = 25;
constexpr int KX    = 128;          // x padded to 128 cols
constexpr int KP    = KX + HID;     // 2176 packed K
constexpr int BK    = 64;
constexpr int KTT   = KP / BK;      // 34 K-steps
constexpr int OSTR  = TDEC * IN;    // 1900 (row stride of decoder_inputs and d_out)

DI unsigned short f2bf(float f) {
  union { float f; unsigned u; } v; v.f = f;
  unsigned u = v.u;
  return (unsigned short)((u + 0x7fffu + ((u >> 16) & 1u)) >> 16);  // RTNE
}

DI f32x4 mfma16(bf16x8 a, bf16x8 b, f32x4 c) {
  return __builtin_amdgcn_mfma_f32_16x16x32_bf16(a, b, c, 0, 0, 0);
}

DI void gload_lds16(const void* g, void* l) {
  __builtin_amdgcn_global_load_lds((const __attribute__((address_space(1))) void*)g,
                                   (__attribute__((address_space(3))) void*)l,
                                   16, 0, 0);
}

DI float sigmoidf_(float x) { return 1.0f / (1.0f + __expf(-x)); }
DI float tanhf_(float x)    { return 1.0f - 2.0f / (1.0f + __expf(2.0f * x)); }

// ---------------- packing kernels (run once per launch) ----------------

__global__ void pack_W(const float* __restrict__ Wih, const float* __restrict__ Whh,
                       ushort_t* __restrict__ Wp) {
  int idx = blockIdx.x * 256 + threadIdx.x;
  if (idx >= 6144 * KP) return;
  int n = idx / KP;
  int k = idx - n * KP;
  float v = 0.f;
  if (k < IN)        v = Wih[(size_t)n * IN + k];
  else if (k >= KX)  v = Whh[(size_t)n * HID + (k - KX)];
  Wp[idx] = f2bf(v);
}

__global__ void pack_xe(const float* __restrict__ enc, ushort_t* __restrict__ xe) {
  int idx = blockIdx.x * 256 + threadIdx.x;
  if (idx >= SENC * BATCH * KX) return;
  int t = idx >> 17;
  int rem = idx & 131071;
  int b = rem >> 7, k = rem & 127;
  float v = (k < IN) ? enc[(size_t)b * (SENC * IN) + t * IN + k] : 0.f;
  xe[idx] = f2bf(v);
}

__global__ void pack_xd0(const float* __restrict__ dec, ushort_t* __restrict__ xd) {
  int idx = blockIdx.x * 256 + threadIdx.x;
  if (idx >= BATCH * KX) return;
  int b = idx >> 7, k = idx & 127;
  float v = (k < IN) ? dec[(size_t)b * OSTR + k] : 0.f;
  xd[idx] = f2bf(v);
}

__global__ void pack_fc(const float* __restrict__ fcw, ushort_t* __restrict__ Wfc) {
  int idx = blockIdx.x * 256 + threadIdx.x;
  if (idx >= 80 * HID) return;
  int n = idx >> 11, k = idx & 2047;
  float v = (n < IN) ? fcw[(size_t)n * HID + k] : 0.f;
  Wfc[idx] = f2bf(v);
}

// ---------------- fused GRU step, software-pipelined dual-phase K-loop ----------------
// grid 256 (8 m-groups x 32 n-groups), block 512 (8 waves, 4x2 over 128x64 tile)
// 3-buffer LDS, stage 2 tiles ahead; ds_reads pipelined one phase ahead so the
// LDS pipe and the MFMA pipe overlap; ONE raw s_barrier per K-step.
__global__ __launch_bounds__(512, 2) void gru_step_kernel(
    const ushort_t* __restrict__ x,    // [1024][128] bf16
    const ushort_t* __restrict__ hbp,  // [1024][2048] bf16 h_prev
    const float*    __restrict__ hfp,  // [1024][2048] f32  h_prev
    const ushort_t* __restrict__ Wp,   // [6144][2176] bf16
    const float*    __restrict__ b_ih,
    const float*    __restrict__ b_hh,
    float*          __restrict__ hfn,  // [1024][2048] f32  h_new
    ushort_t*       __restrict__ hbn)  // [1024][2048] bf16 h_new
{
  __shared__ ushort_t lds[3][(128 + 192) * BK];   // A 128x64 + B 192x64, 3 buffers = 120 KB

  const int tid  = threadIdx.x;
  const int lane = tid & 63;
  const int wid  = tid >> 6;
  const int bid  = blockIdx.x;
  // XCD swizzle: n-group constant per XCD (bid%8) -> W panel reused from one L2
  const int n_grp = (bid & 7) + 8 * (bid >> 6);   // 0..31
  const int m_grp = (bid >> 3) & 7;               // 0..7
  const int row0  = m_grp * 128;
  const int col0  = n_grp * 64;
  const int wm = wid >> 1, wn = wid & 1;

  // staging: chunk row = lane>>3, source col XOR-preswizzled so that the
  // linear global_load_lds destination holds the (row&7)-XOR-swizzled layout
  const int srow  = lane >> 3;
  const int swcol = (((lane & 7) ^ (srow & 7)) << 3);   // elements

  const f32x4 Z4 = {0.f, 0.f, 0.f, 0.f};
  f32x4 accr[2][2], accz[2][2], accin[2][2], accN[2][2];
  #pragma unroll
  for (int a = 0; a < 2; ++a)
    #pragma unroll
    for (int b = 0; b < 2; ++b) { accr[a][b] = Z4; accz[a][b] = Z4; accin[a][b] = Z4; accN[a][b] = Z4; }

  // fragment-read constants (consumer-side XOR swizzle)
  const int lr  = lane & 15;
  const int bc  = (lane >> 4) * 16;                       // byte col, pre-swizzle
  const int ksw0 = ((bc)      ^ ((lane & 7) << 4)) >> 1;  // element offsets
  const int ksw1 = ((64 + bc) ^ ((lane & 7) << 4)) >> 1;

  auto stage = [&](int buf, int kt) {
    const ushort_t* asrc; int astr, ak0;
    if (kt < 2) { asrc = x;   astr = KX;  ak0 = kt * BK; }
    else        { asrc = hbp; astr = HID; ak0 = (kt - 2) * BK; }
    ushort_t* Lb = &lds[buf][0];
    #pragma unroll
    for (int c = 0; c < 2; ++c) {                 // A: 2 chunks/wave (1 KB each)
      const int chunk = wid * 2 + c;
      const ushort_t* g = asrc + (size_t)(row0 + chunk * 8 + srow) * astr + ak0 + swcol;
      gload_lds16(g, Lb + chunk * 512);
    }
    const int wk0 = kt * BK;
    #pragma unroll
    for (int c = 0; c < 3; ++c) {                 // B: 3 chunks/wave
      const int chunk = wid * 3 + c;
      const int brow = chunk * 8 + srow;          // 0..191 (gate*64 + col)
      const int gg = brow >> 6, wi = brow & 63;
      const ushort_t* g = Wp + (size_t)(gg * HID + col0 + wi) * KP + wk0 + swcol;
      gload_lds16(g, Lb + 128 * BK + chunk * 512);
    }
  };

  auto readFrags = [&](const ushort_t* base, int ko, bf16x8 af[2], bf16x8 bg[3][2]) {
    const ushort_t* Ab = base;
    const ushort_t* Bb = base + 128 * BK;
    #pragma unroll
    for (int fm = 0; fm < 2; ++fm)
      af[fm] = *reinterpret_cast<const bf16x8*>(&Ab[(wm * 32 + fm * 16 + lr) * BK + ko]);
    #pragma unroll
    for (int g = 0; g < 3; ++g)
      #pragma unroll
      for (int fn = 0; fn < 2; ++fn)
        bg[g][fn] = *reinterpret_cast<const bf16x8*>(&Bb[(g * 64 + wn * 32 + fn * 16 + lr) * BK + ko]);
  };

  auto burst = [&](bf16x8 af[2], bf16x8 bg[3][2]) {
    __builtin_amdgcn_s_setprio(1);
    #pragma unroll
    for (int fm = 0; fm < 2; ++fm)
      #pragma unroll
      for (int fn = 0; fn < 2; ++fn) {
        accr[fm][fn] = mfma16(af[fm], bg[0][fn], accr[fm][fn]);
        accz[fm][fn] = mfma16(af[fm], bg[1][fn], accz[fm][fn]);
        accN[fm][fn] = mfma16(af[fm], bg[2][fn], accN[fm][fn]);
      }
    __builtin_amdgcn_s_setprio(0);
  };

  // prologue: 2 tiles in flight, tile 0 landed
  stage(0, 0);
  stage(1, 1);
  asm volatile("s_waitcnt vmcnt(5)" ::: "memory");
  __builtin_amdgcn_s_barrier();

  bf16x8 afA[2], bgA[3][2];   // phase-set A (ks0)
  bf16x8 afB[2], bgB[3][2];   // phase-set B (ks1)
  readFrags(&lds[0][0], ksw0, afA, bgA);          // (0, ks0)

  for (int kt = 0; kt < KTT - 1; ++kt) {
    const ushort_t* cur = &lds[kt % 3][0];
    readFrags(cur, ksw1, afB, bgB);               // (kt, ks1) — in flight under burst A
    burst(afA, bgA);                              // compiler emits lgkmcnt(8)-style wait

    asm volatile("s_waitcnt vmcnt(0)" ::: "memory");   // tile kt+1 fully landed
    __builtin_amdgcn_s_barrier();                      // all waves agree; also fences buf reuse
    if (kt + 2 < KTT) stage((kt + 2) % 3, kt + 2);     // refill: safe, one barrier since last reads

    readFrags(&lds[(kt + 1) % 3][0], ksw0, afA, bgA);  // (kt+1, ks0) — in flight under burst B
    burst(afB, bgB);

    if (kt == 1) {   // n-gate: save x-part (i_n), restart accumulator for h-part (h_n)
      #pragma unroll
      for (int a = 0; a < 2; ++a)
        #pragma unroll
        for (int b = 0; b < 2; ++b) { accin[a][b] = accN[a][b]; accN[a][b] = Z4; }
    }
  }
  // peeled last K-step
  {
    const ushort_t* cur = &lds[(KTT - 1) % 3][0];
    readFrags(cur, ksw1, afB, bgB);
    burst(afA, bgA);
    burst(afB, bgB);
  }

  // epilogue: gates + recurrence (C/D layout: col = lane&15, row = (lane>>4)*4 + q)
  const int lqb = (lane >> 4) * 4;
  #pragma unroll
  for (int fn = 0; fn < 2; ++fn) {
    const int j = col0 + wn * 32 + fn * 16 + lr;
    const float br  = b_ih[j] + b_hh[j];
    const float bz  = b_ih[HID + j] + b_hh[HID + j];
    const float bin = b_ih[2 * HID + j];
    const float bhn = b_hh[2 * HID + j];
    #pragma unroll
    for (int fm = 0; fm < 2; ++fm) {
      #pragma unroll
      for (int q = 0; q < 4; ++q) {
        const int row = row0 + wm * 32 + fm * 16 + lqb + q;
        const size_t off = (size_t)row * HID + j;
        const float hp = hfp[off];
        const float rr = sigmoidf_(accr[fm][fn][q] + br);
        const float zz = sigmoidf_(accz[fm][fn][q] + bz);
        const float nn = tanhf_(accin[fm][fn][q] + bin + rr * (accN[fm][fn][q] + bhn));
        const float hv = (1.0f - zz) * nn + zz * hp;
        hfn[off] = hv;
        hbn[off] = f2bf(hv);
      }
    }
  }
}

// ---------------- decoder fc: out = prev + h_new @ fc_w^T + fc_b; also emit next x (bf16) ----
__global__ __launch_bounds__(256) void fc_kernel(
    const ushort_t* __restrict__ hb,    // [1024][2048] bf16 h_new
    const ushort_t* __restrict__ Wfc,   // [80][2048] bf16
    const float*    __restrict__ fc_b,
    const float*    __restrict__ prev,  // row stride OSTR
    float*          __restrict__ outp,  // d_out + t*IN, row stride OSTR
    ushort_t*       __restrict__ xd)    // [1024][128] bf16 next input
{
  __shared__ float red[4][16][80];
  const int tid = threadIdx.x, lane = tid & 63, wid = tid >> 6;
  const int r0 = blockIdx.x * 16;
  const int lr = lane & 15, lk = (lane >> 4) * 8;
  const f32x4 Z4 = {0.f, 0.f, 0.f, 0.f};
  f32x4 acc[5];
  #pragma unroll
  for (int f = 0; f < 5; ++f) acc[f] = Z4;
  const int kbase = wid * 512;
  #pragma unroll
  for (int ks = 0; ks < 16; ++ks) {
    const int k = kbase + ks * 32 + lk;
    bf16x8 a = *reinterpret_cast<const bf16x8*>(&hb[(size_t)(r0 + lr) * HID + k]);
    #pragma unroll
    for (int f = 0; f < 5; ++f) {
      bf16x8 b = *reinterpret_cast<const bf16x8*>(&Wfc[(size_t)(f * 16 + lr) * HID + k]);
      acc[f] = mfma16(a, b, acc[f]);
    }
  }
  #pragma unroll
  for (int f = 0; f < 5; ++f)
    #pragma unroll
    for (int q = 0; q < 4; ++q)
      red[wid][(lane >> 4) * 4 + q][f * 16 + lr] = acc[f][q];
  __syncthreads();

  const int rowi = tid >> 4;          // 0..15
  const int j0   = (tid & 15) * 8;    // 0..120
  const int b_   = r0 + rowi;
  #pragma unroll
  for (int jj = 0; jj < 8; ++jj) {
    const int j = j0 + jj;
    float ov = 0.f;
    if (j < IN) {
      float s = red[0][rowi][j] + red[1][rowi][j] + red[2][rowi][j] + red[3][rowi][j];
      ov = prev[(size_t)b_ * OSTR + j] + fc_b[j] + s;
      outp[(size_t)b_ * OSTR + j] = ov;
    }
    xd[b_ * KX + j] = f2bf(j < IN ? ov : 0.f);
  }
}

// ---------------- host launch ----------------
extern "C" void kernel_launch(void* const* d_in, const int* in_sizes, int n_in,
                              void* d_out, int out_size, void* d_ws, size_t ws_size,
                              hipStream_t stream) {
  const float* enc = (const float*)d_in[0];
  const float* dec = (const float*)d_in[1];
  const float* Wih = (const float*)d_in[2];
  const float* Whh = (const float*)d_in[3];
  const float* bih = (const float*)d_in[4];
  const float* bhh = (const float*)d_in[5];
  const float* fcw = (const float*)d_in[6];
  const float* fcb = (const float*)d_in[7];
  float* out = (float*)d_out;

  char* ws = (char*)d_ws;
  ushort_t* Wp  = (ushort_t*)ws;  ws += (size_t)6144 * KP * 2;          // 26.7 MB
  ushort_t* xe  = (ushort_t*)ws;  ws += (size_t)SENC * BATCH * KX * 2;  // 12.8 MB
  ushort_t* xd  = (ushort_t*)ws;  ws += (size_t)BATCH * KX * 2;         // 256 KB
  ushort_t* Wfc = (ushort_t*)ws;  ws += (size_t)80 * HID * 2;           // 320 KB
  float* hf0 = (float*)ws;        ws += (size_t)BATCH * HID * 4;
  float* hf1 = (float*)ws;        ws += (size_t)BATCH * HID * 4;
  ushort_t* hb0 = (ushort_t*)ws;  ws += (size_t)BATCH * HID * 2;
  ushort_t* hb1 = (ushort_t*)ws;  ws += (size_t)BATCH * HID * 2;
  float* hf[2] = {hf0, hf1};
  ushort_t* hbp[2] = {hb0, hb1};

  pack_W  <<<(6144 * KP + 255) / 256, 256, 0, stream>>>(Wih, Whh, Wp);
  pack_xe <<<(SENC * BATCH * KX + 255) / 256, 256, 0, stream>>>(enc, xe);
  pack_xd0<<<(BATCH * KX + 255) / 256, 256, 0, stream>>>(dec, xd);
  pack_fc <<<(80 * HID + 255) / 256, 256, 0, stream>>>(fcw, Wfc);
  hipMemsetAsync(hf0, 0, (size_t)BATCH * HID * 4, stream);
  hipMemsetAsync(hb0, 0, (size_t)BATCH * HID * 2, stream);

  for (int s = 0; s < SENC + TDEC; ++s) {
    const ushort_t* xsrc = (s < SENC) ? (xe + (size_t)s * BATCH * KX) : xd;
    gru_step_kernel<<<256, 512, 0, stream>>>(xsrc, hbp[s & 1], hf[s & 1], Wp, bih, bhh,
                                             hf[(s + 1) & 1], hbp[(s + 1) & 1]);
    if (s >= SENC) {
      const int t = s - SENC;
      const float* prev = (t == 0) ? dec : (out + (size_t)(t - 1) * IN);
      fc_kernel<<<64, 256, 0, stream>>>(hbp[(s + 1) & 1], Wfc, fcb, prev,
                                        out + (size_t)t * IN, xd);
    }
  }
}

// Round 4
// 2630.998 us; speedup vs baseline: 1.1445x; 1.0386x over previous
//
#include <hip/hip_runtime.h>
#include <cstdint>
#include <cstddef>

#define DI __device__ __forceinline__

typedef __bf16 bf16x8 __attribute__((ext_vector_type(8)));
typedef float  f32x4  __attribute__((ext_vector_type(4)));
typedef unsigned short ushort_t;

constexpr int BATCH = 1024;
constexpr int HID   = 2048;
constexpr int IN    = 76;
constexpr int SENC  = 49;
constexpr int TDEC  = 25;
constexpr int KX    = 128;          // x padded to 128 cols
constexpr int KP    = KX + HID;     // 2176 packed K
constexpr int BK    = 128;          // K-step (one LDS tile)
constexpr int KTT   = KP / BK;      // 17 K-steps
constexpr int OSTR  = TDEC * IN;    // 1900 (row stride of decoder_inputs and d_out)

DI unsigned short f2bf(float f) {
  union { float f; unsigned u; } v; v.f = f;
  unsigned u = v.u;
  return (unsigned short)((u + 0x7fffu + ((u >> 16) & 1u)) >> 16);  // RTNE
}

DI float bf2f(unsigned short h) {
  union { unsigned u; float f; } v; v.u = ((unsigned)h) << 16;
  return v.f;
}

DI f32x4 mfma16(bf16x8 a, bf16x8 b, f32x4 c) {
  return __builtin_amdgcn_mfma_f32_16x16x32_bf16(a, b, c, 0, 0, 0);
}

DI void gload_lds16(const void* g, void* l) {
  __builtin_amdgcn_global_load_lds((const __attribute__((address_space(1))) void*)g,
                                   (__attribute__((address_space(3))) void*)l,
                                   16, 0, 0);
}

DI float sigmoidf_(float x) { return 1.0f / (1.0f + __expf(-x)); }
DI float tanhf_(float x)    { return 1.0f - 2.0f / (1.0f + __expf(2.0f * x)); }

// ---------------- packing kernels (run once per launch) ----------------

__global__ void pack_W(const float* __restrict__ Wih, const float* __restrict__ Whh,
                       ushort_t* __restrict__ Wp) {
  int idx = blockIdx.x * 256 + threadIdx.x;
  if (idx >= 6144 * KP) return;
  int n = idx / KP;
  int k = idx - n * KP;
  float v = 0.f;
  if (k < IN)        v = Wih[(size_t)n * IN + k];
  else if (k >= KX)  v = Whh[(size_t)n * HID + (k - KX)];
  Wp[idx] = f2bf(v);
}

__global__ void pack_xe(const float* __restrict__ enc, ushort_t* __restrict__ xe) {
  int idx = blockIdx.x * 256 + threadIdx.x;
  if (idx >= SENC * BATCH * KX) return;
  int t = idx >> 17;
  int rem = idx & 131071;
  int b = rem >> 7, k = rem & 127;
  float v = (k < IN) ? enc[(size_t)b * (SENC * IN) + t * IN + k] : 0.f;
  xe[idx] = f2bf(v);
}

__global__ void pack_xd0(const float* __restrict__ dec, ushort_t* __restrict__ xd) {
  int idx = blockIdx.x * 256 + threadIdx.x;
  if (idx >= BATCH * KX) return;
  int b = idx >> 7, k = idx & 127;
  float v = (k < IN) ? dec[(size_t)b * OSTR + k] : 0.f;
  xd[idx] = f2bf(v);
}

__global__ void pack_fc(const float* __restrict__ fcw, ushort_t* __restrict__ Wfc) {
  int idx = blockIdx.x * 256 + threadIdx.x;
  if (idx >= 80 * HID) return;
  int n = idx >> 11, k = idx & 2047;
  float v = (n < IN) ? fcw[(size_t)n * HID + k] : 0.f;
  Wfc[idx] = f2bf(v);
}

// ---------------- fused GRU step: BK=128, 2x80KB LDS, 1 barrier + 1 vmcnt per K-step ----
// grid 256 (8 m-groups x 32 n-groups), block 512 (8 waves, 4m x 2n over 128x64 tile)
// Per 128-K iteration: stage(next) at top; 4 quarter-phases of {8 ds_read_b128, 12 MFMA}
// software-pipelined (read Q(q+1) under burst Q(q)); vmcnt(0)+barrier at bottom only.
__global__ __launch_bounds__(512, 2) void gru_step_kernel(
    const ushort_t* __restrict__ x,    // [1024][128] bf16
    const ushort_t* __restrict__ hbp,  // [1024][2048] bf16 h_prev
    const ushort_t* __restrict__ Wp,   // [6144][2176] bf16
    const float*    __restrict__ b_ih,
    const float*    __restrict__ b_hh,
    ushort_t*       __restrict__ hbn)  // [1024][2048] bf16 h_new
{
  // A 128x128 (32 KB) + B 192x128 (48 KB) = 80 KB per buffer, double buffered = 160 KB
  __shared__ ushort_t lds[2][(128 + 192) * BK];

  const int tid  = threadIdx.x;
  const int lane = tid & 63;
  const int wid  = tid >> 6;
  const int bid  = blockIdx.x;
  // XCD swizzle: n-group constant per XCD (bid%8) -> W panel reused from one L2
  const int n_grp = (bid & 7) + 8 * (bid >> 6);   // 0..31
  const int m_grp = (bid >> 3) & 7;               // 0..7
  const int row0  = m_grp * 128;
  const int col0  = n_grp * 64;
  const int wm = wid >> 1, wn = wid & 1;

  const f32x4 Z4 = {0.f, 0.f, 0.f, 0.f};
  f32x4 accr[2][2], accz[2][2], accin[2][2], accN[2][2];
  #pragma unroll
  for (int a = 0; a < 2; ++a)
    #pragma unroll
    for (int b = 0; b < 2; ++b) { accr[a][b] = Z4; accz[a][b] = Z4; accin[a][b] = Z4; accN[a][b] = Z4; }

  const int l15 = lane & 15;
  const int lhi = lane >> 4;                       // 0..3

  // staging: each 1KB chunk = 4 rows x 128 cols; row = chunk*4 + (lane>>4).
  // Source col-chunk pre-XORed with (row & 15) so the linear LDS dest holds the
  // swizzled layout; reader applies the same XOR.
  auto stage = [&](int buf, int kt) {
    const ushort_t* asrc; int astr, ak0;
    if (kt == 0) { asrc = x;   astr = KX;  ak0 = 0; }
    else         { asrc = hbp; astr = HID; ak0 = (kt - 1) * BK; }
    ushort_t* Lb = &lds[buf][0];
    #pragma unroll
    for (int c = 0; c < 4; ++c) {                 // A: 4 chunks/wave
      const int chunk = wid * 4 + c;              // 0..31
      const int rl = chunk * 4 + lhi;             // 0..127
      const int swz = ((l15 ^ (((chunk & 3) << 2) + lhi)) << 3);
      const ushort_t* g = asrc + (size_t)(row0 + rl) * astr + ak0 + swz;
      gload_lds16(g, Lb + chunk * 512);
    }
    const int wk0 = kt * BK;
    #pragma unroll
    for (int c = 0; c < 6; ++c) {                 // B: 6 chunks/wave
      const int chunk = wid * 6 + c;              // 0..47
      const int brow = chunk * 4 + lhi;           // 0..191 (gate*64 + col)
      const int gg = brow >> 6, wi = brow & 63;
      const int swz = ((l15 ^ (((chunk & 3) << 2) + lhi)) << 3);
      const ushort_t* g = Wp + (size_t)(gg * HID + col0 + wi) * KP + wk0 + swz;
      gload_lds16(g, Lb + 128 * BK + chunk * 512);
    }
  };

  // fragment reads: ks in 0..3 selects the 32-k slice; element chunk index
  // = ks*4 + (lane>>4), XORed with (row&15) = (lane&15).
  auto readFrags = [&](const ushort_t* base, int ks, bf16x8 af[2], bf16x8 bg[3][2]) {
    const int el = (((ks << 2) + lhi) ^ l15) << 3;
    #pragma unroll
    for (int fm = 0; fm < 2; ++fm)
      af[fm] = *reinterpret_cast<const bf16x8*>(&base[(wm * 32 + fm * 16 + l15) * BK + el]);
    #pragma unroll
    for (int g = 0; g < 3; ++g)
      #pragma unroll
      for (int fn = 0; fn < 2; ++fn)
        bg[g][fn] = *reinterpret_cast<const bf16x8*>(
            &base[128 * BK + (g * 64 + wn * 32 + fn * 16 + l15) * BK + el]);
  };

  auto burst = [&](bf16x8 af[2], bf16x8 bg[3][2]) {
    __builtin_amdgcn_s_setprio(1);
    #pragma unroll
    for (int fm = 0; fm < 2; ++fm)
      #pragma unroll
      for (int fn = 0; fn < 2; ++fn) {
        accr[fm][fn] = mfma16(af[fm], bg[0][fn], accr[fm][fn]);
        accz[fm][fn] = mfma16(af[fm], bg[1][fn], accz[fm][fn]);
        accN[fm][fn] = mfma16(af[fm], bg[2][fn], accN[fm][fn]);
      }
    __builtin_amdgcn_s_setprio(0);
  };

  bf16x8 afA[2], bgA[3][2];
  bf16x8 afB[2], bgB[3][2];

  // prologue
  stage(0, 0);
  asm volatile("s_waitcnt vmcnt(0)" ::: "memory");
  __builtin_amdgcn_s_barrier();
  readFrags(&lds[0][0], 0, afA, bgA);

  for (int kt = 0; kt < KTT; ++kt) {
    const ushort_t* base = &lds[kt & 1][0];
    if (kt + 1 < KTT) stage((kt + 1) & 1, kt + 1);   // full-iteration latency cover

    readFrags(base, 1, afB, bgB);  burst(afA, bgA);  // Q0
    readFrags(base, 2, afA, bgA);  burst(afB, bgB);  // Q1
    readFrags(base, 3, afB, bgB);  burst(afA, bgA);  // Q2
    burst(afB, bgB);                                 // Q3

    if (kt == 0) {   // k 0..127 done = x-part of n-gate; restart accumulator for h-part
      #pragma unroll
      for (int a = 0; a < 2; ++a)
        #pragma unroll
        for (int b = 0; b < 2; ++b) { accin[a][b] = accN[a][b]; accN[a][b] = Z4; }
    }

    if (kt + 1 < KTT) {
      asm volatile("s_waitcnt vmcnt(0)" ::: "memory");  // tile kt+1 landed
      __builtin_amdgcn_s_barrier();
      readFrags(&lds[(kt + 1) & 1][0], 0, afA, bgA);    // Q0 of next tile
    }
  }

  // epilogue: gates + recurrence, bf16 state only
  // C/D layout: col = lane&15, row = (lane>>4)*4 + q
  const int lqb = lhi * 4;
  #pragma unroll
  for (int fn = 0; fn < 2; ++fn) {
    const int j = col0 + wn * 32 + fn * 16 + l15;
    const float br  = b_ih[j] + b_hh[j];
    const float bz  = b_ih[HID + j] + b_hh[HID + j];
    const float bin = b_ih[2 * HID + j];
    const float bhn = b_hh[2 * HID + j];
    #pragma unroll
    for (int fm = 0; fm < 2; ++fm) {
      #pragma unroll
      for (int q = 0; q < 4; ++q) {
        const int row = row0 + wm * 32 + fm * 16 + lqb + q;
        const size_t off = (size_t)row * HID + j;
        const float hp = bf2f(hbp[off]);
        const float rr = sigmoidf_(accr[fm][fn][q] + br);
        const float zz = sigmoidf_(accz[fm][fn][q] + bz);
        const float nn = tanhf_(accin[fm][fn][q] + bin + rr * (accN[fm][fn][q] + bhn));
        const float hv = (1.0f - zz) * nn + zz * hp;
        hbn[off] = f2bf(hv);
      }
    }
  }
}

// ---------------- decoder fc: out = prev + h_new @ fc_w^T + fc_b; also emit next x (bf16) ----
__global__ __launch_bounds__(256) void fc_kernel(
    const ushort_t* __restrict__ hb,    // [1024][2048] bf16 h_new
    const ushort_t* __restrict__ Wfc,   // [80][2048] bf16
    const float*    __restrict__ fc_b,
    const float*    __restrict__ prev,  // row stride OSTR
    float*          __restrict__ outp,  // d_out + t*IN, row stride OSTR
    ushort_t*       __restrict__ xd)    // [1024][128] bf16 next input
{
  __shared__ float red[4][16][80];
  const int tid = threadIdx.x, lane = tid & 63, wid = tid >> 6;
  const int r0 = blockIdx.x * 16;
  const int lr = lane & 15, lk = (lane >> 4) * 8;
  const f32x4 Z4 = {0.f, 0.f, 0.f, 0.f};
  f32x4 acc[5];
  #pragma unroll
  for (int f = 0; f < 5; ++f) acc[f] = Z4;
  const int kbase = wid * 512;
  #pragma unroll
  for (int ks = 0; ks < 16; ++ks) {
    const int k = kbase + ks * 32 + lk;
    bf16x8 a = *reinterpret_cast<const bf16x8*>(&hb[(size_t)(r0 + lr) * HID + k]);
    #pragma unroll
    for (int f = 0; f < 5; ++f) {
      bf16x8 b = *reinterpret_cast<const bf16x8*>(&Wfc[(size_t)(f * 16 + lr) * HID + k]);
      acc[f] = mfma16(a, b, acc[f]);
    }
  }
  #pragma unroll
  for (int f = 0; f < 5; ++f)
    #pragma unroll
    for (int q = 0; q < 4; ++q)
      red[wid][(lane >> 4) * 4 + q][f * 16 + lr] = acc[f][q];
  __syncthreads();

  const int rowi = tid >> 4;          // 0..15
  const int j0   = (tid & 15) * 8;    // 0..120
  const int b_   = r0 + rowi;
  #pragma unroll
  for (int jj = 0; jj < 8; ++jj) {
    const int j = j0 + jj;
    float ov = 0.f;
    if (j < IN) {
      float s = red[0][rowi][j] + red[1][rowi][j] + red[2][rowi][j] + red[3][rowi][j];
      ov = prev[(size_t)b_ * OSTR + j] + fc_b[j] + s;
      outp[(size_t)b_ * OSTR + j] = ov;
    }
    xd[b_ * KX + j] = f2bf(j < IN ? ov : 0.f);
  }
}

// ---------------- host launch ----------------
extern "C" void kernel_launch(void* const* d_in, const int* in_sizes, int n_in,
                              void* d_out, int out_size, void* d_ws, size_t ws_size,
                              hipStream_t stream) {
  const float* enc = (const float*)d_in[0];
  const float* dec = (const float*)d_in[1];
  const float* Wih = (const float*)d_in[2];
  const float* Whh = (const float*)d_in[3];
  const float* bih = (const float*)d_in[4];
  const float* bhh = (const float*)d_in[5];
  const float* fcw = (const float*)d_in[6];
  const float* fcb = (const float*)d_in[7];
  float* out = (float*)d_out;

  char* ws = (char*)d_ws;
  ushort_t* Wp  = (ushort_t*)ws;  ws += (size_t)6144 * KP * 2;          // 26.7 MB
  ushort_t* xe  = (ushort_t*)ws;  ws += (size_t)SENC * BATCH * KX * 2;  // 12.8 MB
  ushort_t* xd  = (ushort_t*)ws;  ws += (size_t)BATCH * KX * 2;         // 256 KB
  ushort_t* Wfc = (ushort_t*)ws;  ws += (size_t)80 * HID * 2;           // 320 KB
  ushort_t* hb0 = (ushort_t*)ws;  ws += (size_t)BATCH * HID * 2;
  ushort_t* hb1 = (ushort_t*)ws;  ws += (size_t)BATCH * HID * 2;
  ushort_t* hbp[2] = {hb0, hb1};

  pack_W  <<<(6144 * KP + 255) / 256, 256, 0, stream>>>(Wih, Whh, Wp);
  pack_xe <<<(SENC * BATCH * KX + 255) / 256, 256, 0, stream>>>(enc, xe);
  pack_xd0<<<(BATCH * KX + 255) / 256, 256, 0, stream>>>(dec, xd);
  pack_fc <<<(80 * HID + 255) / 256, 256, 0, stream>>>(fcw, Wfc);
  hipMemsetAsync(hb0, 0, (size_t)BATCH * HID * 2, stream);

  for (int s = 0; s < SENC + TDEC; ++s) {
    const ushort_t* xsrc = (s < SENC) ? (xe + (size_t)s * BATCH * KX) : xd;
    gru_step_kernel<<<256, 512, 0, stream>>>(xsrc, hbp[s & 1], Wp, bih, bhh,
                                             hbp[(s + 1) & 1]);
    if (s >= SENC) {
      const int t = s - SENC;
      const float* prev = (t == 0) ? dec : (out + (size_t)(t - 1) * IN);
      fc_kernel<<<64, 256, 0, stream>>>(hbp[(s + 1) & 1], Wfc, fcb, prev,
                                        out + (size_t)t * IN, xd);
    }
  }
}